// Round 1
// baseline (4340.358 us; speedup 1.0000x reference)
//
#include <hip/hip_runtime.h>
#include <hip/hip_bf16.h>

#define HID 101
#define NG 404       // 4*HID
#define NGP 512      // padded gate stride
#define BATCH 1024
#define RPB 4        // batch rows per block
#define NBLK 256     // BATCH/RPB
#define NTHR 512

// ws layout (floats):
//   WT_hh1 : [HID][NGP]  @ 0        (51712)
//   WT_ih2 : [HID][NGP]  @ 51712    (51712)
//   WT_hh2 : [HID][NGP]  @ 103424   (51712)
//   WT_ih1 : [3][NGP]    @ 155136   (1536)
//   b1     : [NGP]       @ 156672   (512)
//   b2     : [NGP]       @ 157184   (512)
#define OFF_WHH1 0
#define OFF_WIH2 51712
#define OFF_WHH2 103424
#define OFF_WIH1 155136
#define OFF_B1   156672
#define OFF_B2   157184

__global__ void prep_kernel(const float* __restrict__ W_ih1, const float* __restrict__ W_hh1,
                            const float* __restrict__ b_ih1, const float* __restrict__ b_hh1,
                            const float* __restrict__ W_ih2, const float* __restrict__ W_hh2,
                            const float* __restrict__ b_ih2, const float* __restrict__ b_hh2,
                            float* __restrict__ ws) {
    int idx = blockIdx.x * blockDim.x + threadIdx.x;
    int stride = gridDim.x * blockDim.x;
    const int NW = HID * NGP;
    for (int i = idx; i < NW; i += stride) {
        int k = i / NGP, g = i % NGP;
        ws[OFF_WHH1 + i] = (g < NG) ? W_hh1[g * HID + k] : 0.f;
        ws[OFF_WIH2 + i] = (g < NG) ? W_ih2[g * HID + k] : 0.f;
        ws[OFF_WHH2 + i] = (g < NG) ? W_hh2[g * HID + k] : 0.f;
    }
    for (int i = idx; i < 3 * NGP; i += stride) {
        int j = i / NGP, g = i % NGP;
        ws[OFF_WIH1 + i] = (g < NG) ? W_ih1[g * 3 + j] : 0.f;
    }
    for (int g = idx; g < NGP; g += stride) {
        ws[OFF_B1 + g] = (g < NG) ? (b_ih1[g] + b_hh1[g]) : 0.f;
        ws[OFF_B2 + g] = (g < NG) ? (b_ih2[g] + b_hh2[g]) : 0.f;
    }
}

__device__ __forceinline__ float sigm(float z) { return 1.f / (1.f + __expf(-z)); }
__device__ __forceinline__ float tanh_f(float z) { return 2.f / (1.f + __expf(-2.f * z)) - 1.f; }

__global__ __launch_bounds__(NTHR, 1) void lstm_kernel(
    const float* __restrict__ input, const float* __restrict__ ws,
    const float* __restrict__ Wl, const float* __restrict__ bl,
    const int* __restrict__ futp, int T, float* __restrict__ out)
{
    const int tid = threadIdx.x;
    const int r0 = blockIdx.x * RPB;
    const int fut = futp[0];
    const int steps = T + fut;
    const int ostride = steps * 3;

    __shared__ float h1[RPB][HID], c1[RPB][HID], h2[RPB][HID], c2[RPB][HID];
    __shared__ float zbuf[RPB][NGP];
    __shared__ float xbuf[RPB][4];
    __shared__ float WlL[3 * HID];
    __shared__ float blL[3];

    const float* WT_hh1 = ws + OFF_WHH1;
    const float* WT_ih2 = ws + OFF_WIH2;
    const float* WT_hh2 = ws + OFF_WHH2;
    const float* WT_ih1 = ws + OFF_WIH1;
    const float* b1 = ws + OFF_B1;
    const float* b2 = ws + OFF_B2;

    // init state
    if (tid < NG) {
        int r = tid / HID, k = tid % HID;
        h1[r][k] = 0.f; c1[r][k] = 0.f; h2[r][k] = 0.f; c2[r][k] = 0.f;
    }
    if (tid < 3 * HID) WlL[tid] = Wl[tid];
    if (tid < 3) blL[tid] = bl[tid];

    for (int t = 0; t < steps; ++t) {
        if (t < T && tid < RPB * 3) {
            int r = tid / 3, j = tid % 3;
            xbuf[r][j] = input[(size_t)(r0 + r) * T * 3 + t * 3 + j];
        }
        __syncthreads();

        // ---- layer 1 gates: z = W_ih1 x + W_hh1 h1 + b1 ----
        if (tid < NG) {
            const int g = tid;
            float z0 = b1[g], z1 = z0, z2 = z0, z3 = z0;
            #pragma unroll
            for (int j = 0; j < 3; ++j) {
                float w = WT_ih1[j * NGP + g];
                z0 += w * xbuf[0][j]; z1 += w * xbuf[1][j];
                z2 += w * xbuf[2][j]; z3 += w * xbuf[3][j];
            }
            for (int k = 0; k < HID; ++k) {
                float w = WT_hh1[k * NGP + g];
                z0 += w * h1[0][k]; z1 += w * h1[1][k];
                z2 += w * h1[2][k]; z3 += w * h1[3][k];
            }
            zbuf[0][g] = z0; zbuf[1][g] = z1; zbuf[2][g] = z2; zbuf[3][g] = z3;
        }
        __syncthreads();

        // ---- layer 1 elementwise ----
        if (tid < NG) {
            int r = tid / HID, k = tid % HID;
            float i_ = sigm(zbuf[r][k]);
            float f_ = sigm(zbuf[r][k + HID]);
            float g_ = tanh_f(zbuf[r][k + 2 * HID]);
            float o_ = sigm(zbuf[r][k + 3 * HID]);
            float c = f_ * c1[r][k] + i_ * g_;
            c1[r][k] = c;
            h1[r][k] = o_ * tanh_f(c);
        }
        __syncthreads();

        // ---- layer 2 gates: z = W_ih2 h1 + W_hh2 h2 + b2 ----
        if (tid < NG) {
            const int g = tid;
            float z0 = b2[g], z1 = z0, z2 = z0, z3 = z0;
            for (int k = 0; k < HID; ++k) {
                float wa = WT_ih2[k * NGP + g];
                float wb = WT_hh2[k * NGP + g];
                z0 += wa * h1[0][k] + wb * h2[0][k];
                z1 += wa * h1[1][k] + wb * h2[1][k];
                z2 += wa * h1[2][k] + wb * h2[2][k];
                z3 += wa * h1[3][k] + wb * h2[3][k];
            }
            zbuf[0][g] = z0; zbuf[1][g] = z1; zbuf[2][g] = z2; zbuf[3][g] = z3;
        }
        __syncthreads();

        // ---- layer 2 elementwise ----
        if (tid < NG) {
            int r = tid / HID, k = tid % HID;
            float i_ = sigm(zbuf[r][k]);
            float f_ = sigm(zbuf[r][k + HID]);
            float g_ = tanh_f(zbuf[r][k + 2 * HID]);
            float o_ = sigm(zbuf[r][k + 3 * HID]);
            float c = f_ * c2[r][k] + i_ * g_;
            c2[r][k] = c;
            h2[r][k] = o_ * tanh_f(c);
        }
        __syncthreads();

        // ---- output: out = h2 @ Wl.T + bl  (12 dots of len 101, 8 lanes each) ----
        if (tid < 96) {
            int grp = tid >> 3, l = tid & 7;
            int r = grp / 3, j = grp % 3;
            float p = 0.f;
            for (int k = l; k < HID; k += 8) p += WlL[j * HID + k] * h2[r][k];
            p += __shfl_down(p, 4, 8);
            p += __shfl_down(p, 2, 8);
            p += __shfl_down(p, 1, 8);
            if (l == 0) {
                p += blL[j];
                out[(size_t)(r0 + r) * ostride + t * 3 + j] = p;
                xbuf[r][j] = p;   // feedback input for future steps
            }
        }
        __syncthreads();
    }
}

extern "C" void kernel_launch(void* const* d_in, const int* in_sizes, int n_in,
                              void* d_out, int out_size, void* d_ws, size_t ws_size,
                              hipStream_t stream) {
    const float* input = (const float*)d_in[0];
    const float* W_ih1 = (const float*)d_in[1];
    const float* W_hh1 = (const float*)d_in[2];
    const float* b_ih1 = (const float*)d_in[3];
    const float* b_hh1 = (const float*)d_in[4];
    const float* W_ih2 = (const float*)d_in[5];
    const float* W_hh2 = (const float*)d_in[6];
    const float* b_ih2 = (const float*)d_in[7];
    const float* b_hh2 = (const float*)d_in[8];
    const float* Wl    = (const float*)d_in[9];
    const float* bl    = (const float*)d_in[10];
    const int*   fut   = (const int*)d_in[11];
    int T = in_sizes[0] / (BATCH * 3);   // = 256
    float* ws = (float*)d_ws;

    hipLaunchKernelGGL(prep_kernel, dim3(64), dim3(256), 0, stream,
                       W_ih1, W_hh1, b_ih1, b_hh1, W_ih2, W_hh2, b_ih2, b_hh2, ws);
    hipLaunchKernelGGL(lstm_kernel, dim3(NBLK), dim3(NTHR), 0, stream,
                       input, ws, Wl, bl, fut, T, (float*)d_out);
}

// Round 2
// 677.024 us; speedup vs baseline: 6.4109x; 6.4109x over previous
//
#include <hip/hip_runtime.h>
#include <hip/hip_bf16.h>

#define HID 101
#define BATCH 1024
#define RPB 4
#define NBLK 256
#define NTHR 512
#define KT1 4
#define KT2 7
#define A1_HALFS (8*4*KT1*512)   // 65536 f16
#define A2_HALFS (8*4*KT2*512)   // 114688 f16

typedef _Float16 h8 __attribute__((ext_vector_type(8)));
typedef _Float16 h4 __attribute__((ext_vector_type(4)));
typedef float f4 __attribute__((ext_vector_type(4)));

// ---------------- prep: pack weights into MFMA A-fragment order (f16) -------------
// Layer1 A: [404+pad gates][K=128]: k<101 -> W_hh1[g][k]; k=112..114 -> W_ih1[g][k-112];
//           k=127 -> fused bias b_ih1+b_hh1 (B row 127 is constant 1).
// Layer2 A: [..][K=224]: k<101 -> W_ih2[g][k]; k=112..212 -> W_hh2[g][k-112]; k=223 -> bias.
// Fragment: lane l holds A[row = l&15][k = kt*32 + (l>>4)*8 + i], i=0..7.
// ws index A1: ((w*4+tau)*KT1+kt)*512 + lane*8 + i ; A2 likewise with KT2, offset A1_HALFS.
__global__ void prep_kernel(const float* __restrict__ W_ih1, const float* __restrict__ W_hh1,
                            const float* __restrict__ b_ih1, const float* __restrict__ b_hh1,
                            const float* __restrict__ W_ih2, const float* __restrict__ W_hh2,
                            const float* __restrict__ b_ih2, const float* __restrict__ b_hh2,
                            _Float16* __restrict__ wsA) {
    int idx = blockIdx.x * blockDim.x + threadIdx.x;
    int stride = gridDim.x * blockDim.x;
    for (int t = idx; t < A1_HALFS; t += stride) {
        int i = t & 7, lane = (t >> 3) & 63, kt = (t >> 9) & 3, tau = (t >> 11) & 3, w = t >> 13;
        int k = kt * 32 + (lane >> 4) * 8 + i;
        int u = 16 * w + (lane & 15);
        int g = tau * HID + u;
        float v = 0.f;
        if (u < HID) {
            if (k < HID) v = W_hh1[g * HID + k];
            else if (k >= 112 && k <= 114) v = W_ih1[g * 3 + (k - 112)];
            else if (k == 127) v = b_ih1[g] + b_hh1[g];
        }
        wsA[t] = (_Float16)v;
    }
    for (int t = idx; t < A2_HALFS; t += stride) {
        int i = t & 7, lane = (t >> 3) & 63;
        int rem = t >> 9;
        int kt = rem % 7; rem /= 7;
        int tau = rem & 3, w = rem >> 2;
        int k = kt * 32 + (lane >> 4) * 8 + i;
        int u = 16 * w + (lane & 15);
        int g = tau * HID + u;
        float v = 0.f;
        if (u < HID) {
            if (k < HID) v = W_ih2[g * HID + k];
            else if (k >= 112 && k <= 212) v = W_hh2[g * HID + (k - 112)];
            else if (k == 223) v = b_ih2[g] + b_hh2[g];
        }
        wsA[A1_HALFS + t] = (_Float16)v;
    }
}

__device__ __forceinline__ float fastrcp(float x) {
#if __has_builtin(__builtin_amdgcn_rcpf)
    return __builtin_amdgcn_rcpf(x);
#else
    return 1.f / x;
#endif
}
__device__ __forceinline__ float sigm(float z) {
    z = fminf(fmaxf(z, -30.f), 30.f);
    return fastrcp(1.f + __expf(-z));
}
__device__ __forceinline__ float tanhf_(float z) {
    z = fminf(fmaxf(z, -15.f), 15.f);
    float e = __expf(-2.f * z);
    return (1.f - e) * fastrcp(1.f + e);
}

// ---------------- main persistent kernel: 256 blocks x 512 thr, 4 rows/block ------
__global__ __launch_bounds__(NTHR, 2) void lstm_kernel(
    const float* __restrict__ input, const _Float16* __restrict__ wsA,
    const float* __restrict__ Wl, const float* __restrict__ bl,
    int T, int steps, float* __restrict__ out)
{
    const int tid = threadIdx.x;
    const int wid = tid >> 6;          // wave id = unit-group
    const int lane = tid & 63;
    const int col = lane & 15;         // batch row (0..3 valid)
    const int q = lane >> 4;           // quadrant
    const int r0 = blockIdx.x * RPB;
    const int u0 = 16 * wid + 4 * q;   // first unit of this lane's C-rows

    __shared__ _Float16 B1f[KT1 * 4 * 16 * 8];   // 4 KB, frag-packed [kt][q][col][i]
    __shared__ _Float16 B2f[KT2 * 4 * 16 * 8];   // 7 KB
    __shared__ float partials[8][4][3];
    __shared__ float blL[3];

    // --- persistent A fragments in VGPRs (176 regs) ---
    h8 A1[4][KT1], A2[4][KT2];
    #pragma unroll
    for (int tau = 0; tau < 4; tau++) {
        #pragma unroll
        for (int kt = 0; kt < KT1; kt++)
            A1[tau][kt] = *reinterpret_cast<const h8*>(
                wsA + ((size_t)((wid * 4 + tau) * KT1 + kt) * 512 + lane * 8));
        #pragma unroll
        for (int kt = 0; kt < KT2; kt++)
            A2[tau][kt] = *reinterpret_cast<const h8*>(
                wsA + (size_t)A1_HALFS + ((size_t)((wid * 4 + tau) * KT2 + kt) * 512 + lane * 8));
    }
    // --- per-lane Wl slice for output partial dots ---
    float wl[12];
    #pragma unroll
    for (int j = 0; j < 3; j++)
        #pragma unroll
        for (int e = 0; e < 4; e++) {
            int u = u0 + e;
            wl[j * 4 + e] = (u < HID) ? Wl[j * HID + u] : 0.f;
        }

    // --- init LDS ---
    for (int i2 = tid; i2 < KT1 * 4 * 16 * 8; i2 += NTHR) B1f[i2] = (_Float16)0.f;
    for (int i2 = tid; i2 < KT2 * 4 * 16 * 8; i2 += NTHR) B2f[i2] = (_Float16)0.f;
    if (tid < 96) ((float*)partials)[tid] = 0.f;
    if (tid < 3) blL[tid] = bl[tid];
    __syncthreads();
    if (tid < 16) {
        B1f[((3 * 4 + 3) * 16 + tid) * 8 + 7] = (_Float16)1.0f;  // k=127 = 1 (bias row)
        B2f[((6 * 4 + 3) * 16 + tid) * 8 + 7] = (_Float16)1.0f;  // k=223 = 1 (bias row)
    }
    if (tid < 12) {                                              // x(0)
        int r = tid / 3, j = tid % 3;
        float v = input[((size_t)(r0 + r) * T + 0) * 3 + j];
        B1f[((3 * 4 + 2) * 16 + r) * 8 + j] = (_Float16)v;       // k=112+j
    }
    float c1[4] = {0, 0, 0, 0}, c2[4] = {0, 0, 0, 0};
    __syncthreads();

    const h8* B1v = reinterpret_cast<const h8*>(B1f);
    const h8* B2v = reinterpret_cast<const h8*>(B2f);
    const int ostride = steps * 3;
    const f4 fzero = {0.f, 0.f, 0.f, 0.f};

    #pragma unroll 1
    for (int t = 0; t < steps; ++t) {
        // ---- layer1 MFMA: z1 = A1 * [x;h1;1] ----
        f4 acc[4];
        #pragma unroll
        for (int tau = 0; tau < 4; tau++) acc[tau] = fzero;
        #pragma unroll
        for (int kt = 0; kt < KT1; kt++) {
            h8 b = B1v[(kt * 4 + q) * 16 + col];
            #pragma unroll
            for (int tau = 0; tau < 4; tau++)
                acc[tau] = __builtin_amdgcn_mfma_f32_16x16x32_f16(A1[tau][kt], b, acc[tau], 0, 0, 0);
        }
        __syncthreads();   // all B1 reads done -> h1 slots writable

        // ---- layer1 elementwise (in-register) ----
        float h1v[4];
        #pragma unroll
        for (int e = 0; e < 4; e++) {
            float ii = sigm(acc[0][e]);
            float ff = sigm(acc[1][e]);
            float gg = tanhf_(acc[2][e]);
            float oo = sigm(acc[3][e]);
            float c = ff * c1[e] + ii * gg;
            c1[e] = c;
            h1v[e] = oo * tanhf_(c);
        }
        if (col < 4 && u0 < HID) {
            h4 hp;
            #pragma unroll
            for (int e = 0; e < 4; e++) hp[e] = (u0 + e < HID) ? (_Float16)h1v[e] : (_Float16)0.f;
            int kt = u0 >> 5, qf = (u0 & 31) >> 3, i0 = u0 & 7;   // i0 in {0,4}
            *reinterpret_cast<h4*>(&B1f[((kt * 4 + qf) * 16 + col) * 8 + i0]) = hp;
            *reinterpret_cast<h4*>(&B2f[((kt * 4 + qf) * 16 + col) * 8 + i0]) = hp;
        }
        __syncthreads();   // h1 visible (h2(t-1) still in B2f)

        // ---- layer2 MFMA: z2 = A2 * [h1;h2;1] ----
        #pragma unroll
        for (int tau = 0; tau < 4; tau++) acc[tau] = fzero;
        #pragma unroll
        for (int kt = 0; kt < KT2; kt++) {
            h8 b = B2v[(kt * 4 + q) * 16 + col];
            #pragma unroll
            for (int tau = 0; tau < 4; tau++)
                acc[tau] = __builtin_amdgcn_mfma_f32_16x16x32_f16(A2[tau][kt], b, acc[tau], 0, 0, 0);
        }
        __syncthreads();   // all B2 reads done -> h2 slots writable

        // ---- layer2 elementwise ----
        float h2v[4];
        #pragma unroll
        for (int e = 0; e < 4; e++) {
            float ii = sigm(acc[0][e]);
            float ff = sigm(acc[1][e]);
            float gg = tanhf_(acc[2][e]);
            float oo = sigm(acc[3][e]);
            float c = ff * c2[e] + ii * gg;
            c2[e] = c;
            h2v[e] = oo * tanhf_(c);
        }
        if (col < 4 && u0 < HID) {
            h4 hp;
            #pragma unroll
            for (int e = 0; e < 4; e++) hp[e] = (u0 + e < HID) ? (_Float16)h2v[e] : (_Float16)0.f;
            int k0 = 112 + u0;
            int kt = k0 >> 5, qf = (k0 & 31) >> 3, i0 = k0 & 7;
            *reinterpret_cast<h4*>(&B2f[((kt * 4 + qf) * 16 + col) * 8 + i0]) = hp;
        }
        // ---- output partial dots: out[r][j] = sum_u h2[u][r]*Wl[j][u] ----
        float p0 = wl[0] * h2v[0] + wl[1] * h2v[1] + wl[2] * h2v[2] + wl[3] * h2v[3];
        float p1 = wl[4] * h2v[0] + wl[5] * h2v[1] + wl[6] * h2v[2] + wl[7] * h2v[3];
        float p2 = wl[8] * h2v[0] + wl[9] * h2v[1] + wl[10] * h2v[2] + wl[11] * h2v[3];
        p0 += __shfl_xor(p0, 16); p0 += __shfl_xor(p0, 32);
        p1 += __shfl_xor(p1, 16); p1 += __shfl_xor(p1, 32);
        p2 += __shfl_xor(p2, 16); p2 += __shfl_xor(p2, 32);
        if (lane < 4) {
            partials[wid][lane][0] = p0;
            partials[wid][lane][1] = p1;
            partials[wid][lane][2] = p2;
        }
        // ---- stage next input x(t+1) (teacher-forced phase) ----
        if (t + 1 < T && tid < 12) {
            int r = tid / 3, j = tid % 3;
            float v = input[((size_t)(r0 + r) * T + (t + 1)) * 3 + j];
            B1f[((3 * 4 + 2) * 16 + r) * 8 + j] = (_Float16)v;
        }
        __syncthreads();   // partials + h2 visible

        // ---- finalize output; feedback x for future phase ----
        if (tid < 12) {
            int r = tid / 3, j = tid % 3;
            float s = blL[j];
            #pragma unroll
            for (int w2 = 0; w2 < 8; w2++) s += partials[w2][r][j];
            out[(size_t)(r0 + r) * ostride + t * 3 + j] = s;
            if (t + 1 >= T && t + 1 < steps)
                B1f[((3 * 4 + 2) * 16 + r) * 8 + j] = (_Float16)s;
        }
        __syncthreads();   // next-step L1 may read x
    }
}

extern "C" void kernel_launch(void* const* d_in, const int* in_sizes, int n_in,
                              void* d_out, int out_size, void* d_ws, size_t ws_size,
                              hipStream_t stream) {
    const float* input = (const float*)d_in[0];
    const float* W_ih1 = (const float*)d_in[1];
    const float* W_hh1 = (const float*)d_in[2];
    const float* b_ih1 = (const float*)d_in[3];
    const float* b_hh1 = (const float*)d_in[4];
    const float* W_ih2 = (const float*)d_in[5];
    const float* W_hh2 = (const float*)d_in[6];
    const float* b_ih2 = (const float*)d_in[7];
    const float* b_hh2 = (const float*)d_in[8];
    const float* Wl    = (const float*)d_in[9];
    const float* bl    = (const float*)d_in[10];
    int T = in_sizes[0] / (BATCH * 3);        // 256
    int steps = out_size / (BATCH * 3);       // 288
    _Float16* wsA = (_Float16*)d_ws;

    hipLaunchKernelGGL(prep_kernel, dim3(512), dim3(256), 0, stream,
                       W_ih1, W_hh1, b_ih1, b_hh1, W_ih2, W_hh2, b_ih2, b_hh2, wsA);
    hipLaunchKernelGGL(lstm_kernel, dim3(NBLK), dim3(NTHR), 0, stream,
                       input, wsA, Wl, bl, T, steps, (float*)d_out);
}

// Round 3
// 481.509 us; speedup vs baseline: 9.0141x; 1.4060x over previous
//
#include <hip/hip_runtime.h>
#include <hip/hip_bf16.h>

#define HID 101
#define BATCH 1024
#define RPB 4
#define NBLK 256
#define NTHR 512

#define A1SZ  (7*4*4*512)    // 57344 halfs
#define A2SZ  (7*4*8*512)    // 114688 halfs
#define A2OFF A1SZ
#define AOOFF (A1SZ + A2SZ)  // 172032
#define AOSZ  (4*512)

typedef _Float16 h8 __attribute__((ext_vector_type(8)));
typedef float f4 __attribute__((ext_vector_type(4)));

// ---------------------------------------------------------------------------
// prep: pack A-operand fragments (f16) for mfma_f32_16x16x32_f16.
// Fragment: lane l holds A[row=l&15][k = kt*32 + (l>>4)*8 + i], i=0..7.
// L1 (A1, KT=4, K=128): k<101 -> W_hh1[g][k]; k=101..103 -> W_ih1[g][k-101];
//                       k==104 -> b_ih1[g]+b_hh1[g] (B k=104 slot is const 1).
// L2 (A2, KT=8, K=256): k<101 -> W_ih2[g][k]; k==104 -> b_ih2[g]+b_hh2[g];
//                       k=128..228 -> W_hh2[g][k-128].
// Aout (4 frags over h2 region): row j<3: k<101 -> Wl[j][k].
// ---------------------------------------------------------------------------
__global__ void prep_kernel(const float* __restrict__ W_ih1, const float* __restrict__ W_hh1,
                            const float* __restrict__ b_ih1, const float* __restrict__ b_hh1,
                            const float* __restrict__ W_ih2, const float* __restrict__ W_hh2,
                            const float* __restrict__ b_ih2, const float* __restrict__ b_hh2,
                            const float* __restrict__ Wl, _Float16* __restrict__ wsA) {
    int idx = blockIdx.x * blockDim.x + threadIdx.x;
    int stride = gridDim.x * blockDim.x;
    for (int t = idx; t < A1SZ; t += stride) {
        int i = t & 7, lane = (t >> 3) & 63, kt = (t >> 9) & 3, tau = (t >> 11) & 3, w = t >> 13;
        int k = kt * 32 + ((lane >> 4) & 3) * 8 + i;
        int u = 16 * w + (lane & 15);
        float v = 0.f;
        if (u < HID) {
            int g = tau * HID + u;
            if (k < HID) v = W_hh1[g * HID + k];
            else if (k >= 101 && k <= 103) v = W_ih1[g * 3 + (k - 101)];
            else if (k == 104) v = b_ih1[g] + b_hh1[g];
        }
        wsA[t] = (_Float16)v;
    }
    for (int t = idx; t < A2SZ; t += stride) {
        int i = t & 7, lane = (t >> 3) & 63, kt = (t >> 9) & 7, tau = (t >> 12) & 3, w = t >> 14;
        int k = kt * 32 + ((lane >> 4) & 3) * 8 + i;
        int u = 16 * w + (lane & 15);
        float v = 0.f;
        if (u < HID) {
            int g = tau * HID + u;
            if (k < HID) v = W_ih2[g * HID + k];
            else if (k == 104) v = b_ih2[g] + b_hh2[g];
            else if (k >= 128 && k < 128 + HID) v = W_hh2[g * HID + (k - 128)];
        }
        wsA[A2OFF + t] = (_Float16)v;
    }
    for (int t = idx; t < AOSZ; t += stride) {
        int i = t & 7, lane = (t >> 3) & 63, kt = (t >> 9) & 3;
        int k = kt * 32 + ((lane >> 4) & 3) * 8 + i;
        int j = lane & 15;
        float v = (j < 3 && k < HID) ? Wl[j * HID + k] : 0.f;
        wsA[AOOFF + t] = (_Float16)v;
    }
}

__device__ __forceinline__ float sigm(float z) {
    return __builtin_amdgcn_rcpf(1.f + __expf(-z));
}
__device__ __forceinline__ float tanhf_(float z) {
    // 1 - 2/(exp(2z)+1): saturates cleanly to +/-1 without clamps (inf/0 safe)
    return 1.f - 2.f * __builtin_amdgcn_rcpf(__expf(2.f * z) + 1.f);
}

#define KEEP(x) { f4 _kv = __builtin_bit_cast(f4, x); asm volatile("" : "+v"(_kv)); \
                  x = __builtin_bit_cast(h8, _kv); }

// ---------------------------------------------------------------------------
// persistent kernel: 256 blocks x 512 thr (8 waves). Waves 0-6: units 16w..16w+15
// (all 4 gates via 4 M-tiles). Wave 7: out-MFMA + x staging/feedback.
// ---------------------------------------------------------------------------
__global__ __launch_bounds__(NTHR, 2) void lstm_kernel(
    const float* __restrict__ input, const _Float16* __restrict__ wsA,
    const float* __restrict__ bl, int T, int steps, float* __restrict__ out)
{
    const int tid = threadIdx.x;
    const int wid = tid >> 6, lane = tid & 63;
    const int q = lane >> 4, col = lane & 15;
    const int r0 = blockIdx.x * RPB;
    const int ostride = steps * 3;

    __shared__ _Float16 Hb[2][2048];   // h1 (k<101) + x (k101..103) + bias=1 (k104)
    __shared__ _Float16 K2b[2][2048];  // h2 (k<101)
    __shared__ float zw[7][4][4][16];  // per-wave z exchange [wid][tau][r][u_local]

    h8 A1[4][4];
    h8 A2[4][8];
    if (wid < 7) {
        #pragma unroll
        for (int tau = 0; tau < 4; tau++) {
            #pragma unroll
            for (int kt = 0; kt < 4; kt++) {
                A1[tau][kt] = *(const h8*)(wsA + (size_t)(((wid * 4 + tau) * 4 + kt) * 64 + lane) * 8);
                KEEP(A1[tau][kt]);
            }
            #pragma unroll
            for (int kt = 0; kt < 8; kt++) {
                A2[tau][kt] = *(const h8*)(wsA + (size_t)A2OFF + (size_t)(((wid * 4 + tau) * 8 + kt) * 64 + lane) * 8);
                KEEP(A2[tau][kt]);
            }
        }
    } else {
        #pragma unroll
        for (int kt = 0; kt < 4; kt++) {
            A2[0][kt] = *(const h8*)(wsA + (size_t)AOOFF + (size_t)(kt * 64 + lane) * 8);
            KEEP(A2[0][kt]);
        }
    }
    const float bl0 = bl[0], bl1 = bl[1], bl2 = bl[2];   // uniform -> SGPR

    // loop-invariant lane geometry
    const int r_ew = lane & 3, ul = lane >> 2;
    const int u = 16 * wid + ul;
    const bool ewv = (wid < 7) && (u < HID);
    const int hslot = (((u >> 5) * 4 + ((u >> 3) & 3)) * 16 + r_ew) * 8 + (u & 7);
    const int boff = (q * 16 + col) * 8;
    const int xr = lane / 3, xj = lane - 3 * xr;              // wave7 lanes<12
    const int xoff = ((12 + 0) * 16 + xr) * 8 + 5 + xj;       // x slot (k=101+xj, col=xr)

    // ---- prologue ----
    for (int i2 = tid; i2 < 2048; i2 += NTHR) {
        Hb[0][i2] = (_Float16)0.f; Hb[1][i2] = (_Float16)0.f;
        K2b[0][i2] = (_Float16)0.f; K2b[1][i2] = (_Float16)0.f;
    }
    __syncthreads();
    if (tid < 16) {   // bias slot k=104 (kt=3, qf=1, i=0), all cols
        Hb[0][((12 + 1) * 16 + tid) * 8] = (_Float16)1.0f;
        Hb[1][((12 + 1) * 16 + tid) * 8] = (_Float16)1.0f;
    }
    if (tid < 12) {   // x(0) -> Hb[1]
        int r = tid / 3, j = tid - 3 * (tid / 3);
        float v = input[(size_t)(r0 + r) * T * 3 + j];
        Hb[1][((12 + 0) * 16 + r) * 8 + 5 + j] = (_Float16)v;
    }
    float c1 = 0.f, c2 = 0.f;
    __syncthreads();

    auto STEP = [&](int t, _Float16* Hrd, _Float16* Hwr, _Float16* K2rd, _Float16* K2wr, bool fut) {
        float xv = 0.f;
        if (fut) {
            // out(t-1) must be ready before L1(t) reads x slots
            if (wid == 7) {
                f4 ao = {0.f, 0.f, 0.f, 0.f};
                #pragma unroll
                for (int kt = 0; kt < 4; kt++) {
                    h8 b = *(const h8*)(K2rd + kt * 512 + boff);
                    ao = __builtin_amdgcn_mfma_f32_16x16x32_f16(A2[0][kt], b, ao, 0, 0, 0);
                }
                if (lane < 4) {
                    float o0 = ao[0] + bl0, o1 = ao[1] + bl1, o2 = ao[2] + bl2;
                    float* op = out + (size_t)(r0 + lane) * ostride + (size_t)(t - 1) * 3;
                    op[0] = o0; op[1] = o1; op[2] = o2;
                    Hrd[(12 * 16 + lane) * 8 + 5] = (_Float16)o0;
                    Hrd[(12 * 16 + lane) * 8 + 6] = (_Float16)o1;
                    Hrd[(12 * 16 + lane) * 8 + 7] = (_Float16)o2;
                }
            }
            __syncthreads();
        }
        // ---- phase A: L1 MFMA + ew1 ; wave7: out(t-1) + x load ----
        if (wid < 7) {
            f4 acc0 = {0.f,0.f,0.f,0.f}, acc1 = acc0, acc2 = acc0, acc3 = acc0;
            #pragma unroll
            for (int kt = 0; kt < 4; kt++) {
                h8 b = *(const h8*)(Hrd + kt * 512 + boff);
                acc0 = __builtin_amdgcn_mfma_f32_16x16x32_f16(A1[0][kt], b, acc0, 0, 0, 0);
                acc1 = __builtin_amdgcn_mfma_f32_16x16x32_f16(A1[1][kt], b, acc1, 0, 0, 0);
                acc2 = __builtin_amdgcn_mfma_f32_16x16x32_f16(A1[2][kt], b, acc2, 0, 0, 0);
                acc3 = __builtin_amdgcn_mfma_f32_16x16x32_f16(A1[3][kt], b, acc3, 0, 0, 0);
            }
            if (col < 4) {
                *(f4*)&zw[wid][0][col][4 * q] = acc0;
                *(f4*)&zw[wid][1][col][4 * q] = acc1;
                *(f4*)&zw[wid][2][col][4 * q] = acc2;
                *(f4*)&zw[wid][3][col][4 * q] = acc3;
            }
            float z0 = zw[wid][0][r_ew][ul], z1 = zw[wid][1][r_ew][ul];
            float z2 = zw[wid][2][r_ew][ul], z3 = zw[wid][3][r_ew][ul];
            float ig = sigm(z0), fg = sigm(z1), gg = tanhf_(z2), og = sigm(z3);
            c1 = fg * c1 + ig * gg;
            float h1v = og * tanhf_(c1);
            if (ewv) Hwr[hslot] = (_Float16)h1v;
        } else {
            if (!fut) {
                if (t > 0) {
                    f4 ao = {0.f, 0.f, 0.f, 0.f};
                    #pragma unroll
                    for (int kt = 0; kt < 4; kt++) {
                        h8 b = *(const h8*)(K2rd + kt * 512 + boff);
                        ao = __builtin_amdgcn_mfma_f32_16x16x32_f16(A2[0][kt], b, ao, 0, 0, 0);
                    }
                    if (lane < 4) {
                        float* op = out + (size_t)(r0 + lane) * ostride + (size_t)(t - 1) * 3;
                        op[0] = ao[0] + bl0; op[1] = ao[1] + bl1; op[2] = ao[2] + bl2;
                    }
                }
                if (t + 1 < T && lane < 12)
                    xv = input[(size_t)(r0 + xr) * T * 3 + (size_t)(t + 1) * 3 + xj];
            }
        }
        __syncthreads();   // M: h1(t) visible
        // ---- phase B: L2 MFMA + ew2 ; wave7: stage x(t+1) ----
        if (wid < 7) {
            f4 acc0 = {0.f,0.f,0.f,0.f}, acc1 = acc0, acc2 = acc0, acc3 = acc0;
            #pragma unroll
            for (int kt = 0; kt < 4; kt++) {
                h8 b = *(const h8*)(Hwr + kt * 512 + boff);
                acc0 = __builtin_amdgcn_mfma_f32_16x16x32_f16(A2[0][kt], b, acc0, 0, 0, 0);
                acc1 = __builtin_amdgcn_mfma_f32_16x16x32_f16(A2[1][kt], b, acc1, 0, 0, 0);
                acc2 = __builtin_amdgcn_mfma_f32_16x16x32_f16(A2[2][kt], b, acc2, 0, 0, 0);
                acc3 = __builtin_amdgcn_mfma_f32_16x16x32_f16(A2[3][kt], b, acc3, 0, 0, 0);
            }
            #pragma unroll
            for (int kt = 0; kt < 4; kt++) {
                h8 b = *(const h8*)(K2rd + kt * 512 + boff);
                acc0 = __builtin_amdgcn_mfma_f32_16x16x32_f16(A2[0][kt + 4], b, acc0, 0, 0, 0);
                acc1 = __builtin_amdgcn_mfma_f32_16x16x32_f16(A2[1][kt + 4], b, acc1, 0, 0, 0);
                acc2 = __builtin_amdgcn_mfma_f32_16x16x32_f16(A2[2][kt + 4], b, acc2, 0, 0, 0);
                acc3 = __builtin_amdgcn_mfma_f32_16x16x32_f16(A2[3][kt + 4], b, acc3, 0, 0, 0);
            }
            if (col < 4) {
                *(f4*)&zw[wid][0][col][4 * q] = acc0;
                *(f4*)&zw[wid][1][col][4 * q] = acc1;
                *(f4*)&zw[wid][2][col][4 * q] = acc2;
                *(f4*)&zw[wid][3][col][4 * q] = acc3;
            }
            float z0 = zw[wid][0][r_ew][ul], z1 = zw[wid][1][r_ew][ul];
            float z2 = zw[wid][2][r_ew][ul], z3 = zw[wid][3][r_ew][ul];
            float ig = sigm(z0), fg = sigm(z1), gg = tanhf_(z2), og = sigm(z3);
            c2 = fg * c2 + ig * gg;
            float h2v = og * tanhf_(c2);
            if (ewv) K2wr[hslot] = (_Float16)h2v;
        } else {
            if (!fut && t + 1 < T && lane < 12)
                Hwr[xoff] = (_Float16)xv;
        }
        __syncthreads();   // E: h2(t) + x(t+1) visible
    };

    for (int t = 0; t < T; t += 2) {
        STEP(t,     Hb[1], Hb[0], K2b[1], K2b[0], false);
        STEP(t + 1, Hb[0], Hb[1], K2b[0], K2b[1], false);
    }
    for (int t = T; t < steps; t += 2) {
        STEP(t,     Hb[1], Hb[0], K2b[1], K2b[0], true);
        STEP(t + 1, Hb[0], Hb[1], K2b[0], K2b[1], true);
    }
    // epilogue: out(steps-1) from h2(steps-1) in K2b[1]  (steps-1 odd)
    if (wid == 7) {
        f4 ao = {0.f, 0.f, 0.f, 0.f};
        #pragma unroll
        for (int kt = 0; kt < 4; kt++) {
            h8 b = *(const h8*)(&K2b[1][0] + kt * 512 + boff);
            ao = __builtin_amdgcn_mfma_f32_16x16x32_f16(A2[0][kt], b, ao, 0, 0, 0);
        }
        if (lane < 4) {
            float* op = out + (size_t)(r0 + lane) * ostride + (size_t)(steps - 1) * 3;
            op[0] = ao[0] + bl0; op[1] = ao[1] + bl1; op[2] = ao[2] + bl2;
        }
    }
}

extern "C" void kernel_launch(void* const* d_in, const int* in_sizes, int n_in,
                              void* d_out, int out_size, void* d_ws, size_t ws_size,
                              hipStream_t stream) {
    const float* input = (const float*)d_in[0];
    const float* W_ih1 = (const float*)d_in[1];
    const float* W_hh1 = (const float*)d_in[2];
    const float* b_ih1 = (const float*)d_in[3];
    const float* b_hh1 = (const float*)d_in[4];
    const float* W_ih2 = (const float*)d_in[5];
    const float* W_hh2 = (const float*)d_in[6];
    const float* b_ih2 = (const float*)d_in[7];
    const float* b_hh2 = (const float*)d_in[8];
    const float* Wl    = (const float*)d_in[9];
    const float* bl    = (const float*)d_in[10];
    int T = in_sizes[0] / (BATCH * 3);        // 256
    int steps = out_size / (BATCH * 3);       // 288
    _Float16* wsA = (_Float16*)d_ws;

    hipLaunchKernelGGL(prep_kernel, dim3(512), dim3(256), 0, stream,
                       W_ih1, W_hh1, b_ih1, b_hh1, W_ih2, W_hh2, b_ih2, b_hh2, Wl, wsA);
    hipLaunchKernelGGL(lstm_kernel, dim3(NBLK), dim3(NTHR), 0, stream,
                       input, wsA, bl, T, steps, (float*)d_out);
}